// Round 1
// baseline (370.196 us; speedup 1.0000x reference)
//
#include <hip/hip_runtime.h>
#include <hip/hip_bf16.h>

// Problem constants (from setup_inputs)
#define B 4
#define N 2048
#define D 512
#define H 8
#define DH 64
#define ROWS (B * N)        // 8192
#define WIN 64              // truncation window; r<=0.764 -> r^64 ~ 3e-8

// ---------------- f32 tiled GEMM: C[M,Nn] = A[M,K] @ Bm[K,Nn] (+bias) ----------
#define BM 64
#define BN 64
#define BK 16

__global__ __launch_bounds__(256) void gemm_f32(const float* __restrict__ A,
                                                const float* __restrict__ Bm,
                                                const float* __restrict__ bias,
                                                float* __restrict__ C,
                                                int M, int Nn, int K) {
    __shared__ alignas(16) float As[BK][BM + 4];
    __shared__ alignas(16) float Bs[BK][BN + 4];

    const int bn = blockIdx.x;   // along Nn
    const int bm = blockIdx.y;   // along M
    const int tid = threadIdx.x;
    const int tr = tid / 16;     // 0..15
    const int tc = tid % 16;     // 0..15

    float acc[4][4] = {};

    for (int k0 = 0; k0 < K; k0 += BK) {
        // Load A tile 64x16 (float4 per thread): r = tid>>2 (0..63), c4 = tid&3
        {
            const int r = tid >> 2, c4 = tid & 3;
            const float4 av = *reinterpret_cast<const float4*>(
                &A[(long long)(bm * BM + r) * K + k0 + c4 * 4]);
            As[c4 * 4 + 0][r] = av.x;
            As[c4 * 4 + 1][r] = av.y;
            As[c4 * 4 + 2][r] = av.z;
            As[c4 * 4 + 3][r] = av.w;
        }
        // Load B tile 16x64 (float4 per thread): r = tid>>4 (0..15), c4 = tid&15
        {
            const int r = tid >> 4, c4 = tid & 15;
            const float4 bv = *reinterpret_cast<const float4*>(
                &Bm[(long long)(k0 + r) * Nn + bn * BN + c4 * 4]);
            *reinterpret_cast<float4*>(&Bs[r][c4 * 4]) = bv;
        }
        __syncthreads();

#pragma unroll
        for (int kk = 0; kk < BK; kk++) {
            float a[4], b[4];
            const float4 a4 = *reinterpret_cast<const float4*>(&As[kk][tr * 4]);
            const float4 b4 = *reinterpret_cast<const float4*>(&Bs[kk][tc * 4]);
            a[0] = a4.x; a[1] = a4.y; a[2] = a4.z; a[3] = a4.w;
            b[0] = b4.x; b[1] = b4.y; b[2] = b4.z; b[3] = b4.w;
#pragma unroll
            for (int ii = 0; ii < 4; ii++)
#pragma unroll
                for (int jj = 0; jj < 4; jj++)
                    acc[ii][jj] += a[ii] * b[jj];
        }
        __syncthreads();
    }

#pragma unroll
    for (int ii = 0; ii < 4; ii++) {
        const int row = bm * BM + tr * 4 + ii;
#pragma unroll
        for (int jj = 0; jj < 4; jj++) {
            const int col = bn * BN + tc * 4 + jj;
            float v = acc[ii][jj];
            if (bias) v += bias[col];
            C[(long long)row * Nn + col] = v;
        }
    }
}

// ---------------- sigma -> r = exp(-1/(exp(sigmoid(x@Ws+bs))+1)) --------------
// one thread per (row, h); rbuf layout: [row][h] (row = b*N + i)
__global__ __launch_bounds__(256) void sigma_kernel(const float* __restrict__ x,
                                                    const float* __restrict__ Ws,
                                                    const float* __restrict__ bs,
                                                    float* __restrict__ rbuf) {
    const int gid = blockIdx.x * 256 + threadIdx.x;   // row*8 + h
    const int row = gid >> 3;
    const int h = gid & 7;
    const float* xr = x + (long long)row * D;
    float acc = 0.f;
#pragma unroll 8
    for (int e = 0; e < D; e++) acc += xr[e] * Ws[e * H + h];
    const float z = acc + bs[h];
    const float sig = 1.0f / (1.0f + expf(-z));
    const float s = expf(sig) + 1.0f;
    rbuf[gid] = expf(-1.0f / s);
}

// ---------------- windowed geometric-decay attention --------------------------
// one wave (64 lanes) per (b,h,i) row; lane = dh index
__global__ __launch_bounds__(256) void attn_win(const float* __restrict__ V,
                                                const float* __restrict__ rbuf,
                                                float* __restrict__ O) {
    const int wid = threadIdx.x >> 6;
    const int lane = threadIdx.x & 63;
    const long long gi = (long long)blockIdx.x * 4 + wid;  // over B*H*N
    const int i = (int)(gi % N);
    const int bh = (int)(gi / N);
    const int h = bh % H;
    const int b = bh / H;

    const float* Vb = V + (long long)b * N * D + h * DH + lane;   // column slice
    const float r = rbuf[(((long long)b * N + i)) * H + h];

    float acc = Vb[(long long)i * D];   // t = 0, weight 1
    float z = 1.0f;
    float w = 1.0f;
#pragma unroll 4
    for (int t = 1; t <= WIN; t++) {
        w *= r;
        const int jl = i - t;
        const int jr = i + t;
        if (jl >= 0) { acc += w * Vb[(long long)jl * D]; z += w; }
        if (jr < N)  { acc += w * Vb[(long long)jr * D]; z += w; }
    }
    O[((long long)b * N + i) * D + h * DH + lane] = acc / z;
}

extern "C" void kernel_launch(void* const* d_in, const int* in_sizes, int n_in,
                              void* d_out, int out_size, void* d_ws, size_t ws_size,
                              hipStream_t stream) {
    const float* x      = (const float*)d_in[0];   // (B,N,D)
    const float* W_v    = (const float*)d_in[1];   // (D, H*DH)
    const float* W_sig  = (const float*)d_in[2];   // (D, H)
    const float* b_sig  = (const float*)d_in[3];   // (H,)
    const float* W_out  = (const float*)d_in[4];   // (H*DH, D)
    const float* b_out  = (const float*)d_in[5];   // (D,)
    float* out = (float*)d_out;

    char* ws = (char*)d_ws;
    float* V       = (float*)(ws);                              // ROWS*D f32 = 16 MB
    float* attnOut = (float*)(ws + (size_t)ROWS * D * 4);       // 16 MB
    float* rbuf    = (float*)(ws + (size_t)ROWS * D * 8);       // ROWS*H f32 = 256 KB

    // 1) V = x @ W_v
    {
        dim3 grid(D / BN, ROWS / BM);
        gemm_f32<<<grid, 256, 0, stream>>>(x, W_v, nullptr, V, ROWS, D, D);
    }
    // 2) r per (row, h)
    {
        dim3 grid(ROWS * H / 256);
        sigma_kernel<<<grid, 256, 0, stream>>>(x, W_sig, b_sig, rbuf);
    }
    // 3) windowed attention
    {
        dim3 grid(B * H * N / 4);
        attn_win<<<grid, 256, 0, stream>>>(V, rbuf, attnOut);
    }
    // 4) out = attnOut @ W_out + b_out
    {
        dim3 grid(D / BN, ROWS / BM);
        gemm_f32<<<grid, 256, 0, stream>>>(attnOut, W_out, b_out, out, ROWS, D, D);
    }
}

// Round 2
// 214.318 us; speedup vs baseline: 1.7273x; 1.7273x over previous
//
#include <hip/hip_runtime.h>
#include <hip/hip_bf16.h>

// Problem constants (from setup_inputs)
#define B 4
#define N 2048
#define D 512
#define H 8
#define DH 64
#define ROWS (B * N)        // 8192
#define WIN 64              // truncation window; r<=0.764 -> r^64 ~ 3e-8
#define QB 16               // query rows per wave in attn_sweep

// ---------------- f32 tiled GEMM: C[M,Nn] = A[M,K] @ Bm[K,Nn] (+bias) ----------
#define BM 64
#define BN 64
#define BK 16

__global__ __launch_bounds__(256) void gemm_f32(const float* __restrict__ A,
                                                const float* __restrict__ Bm,
                                                const float* __restrict__ bias,
                                                float* __restrict__ C,
                                                int M, int Nn, int K) {
    __shared__ alignas(16) float As[BK][BM + 4];
    __shared__ alignas(16) float Bs[BK][BN + 4];

    const int bn = blockIdx.x;   // along Nn
    const int bm = blockIdx.y;   // along M
    const int tid = threadIdx.x;
    const int tr = tid / 16;     // 0..15
    const int tc = tid % 16;     // 0..15

    float acc[4][4] = {};

    for (int k0 = 0; k0 < K; k0 += BK) {
        {
            const int r = tid >> 2, c4 = tid & 3;
            const float4 av = *reinterpret_cast<const float4*>(
                &A[(long long)(bm * BM + r) * K + k0 + c4 * 4]);
            As[c4 * 4 + 0][r] = av.x;
            As[c4 * 4 + 1][r] = av.y;
            As[c4 * 4 + 2][r] = av.z;
            As[c4 * 4 + 3][r] = av.w;
        }
        {
            const int r = tid >> 4, c4 = tid & 15;
            const float4 bv = *reinterpret_cast<const float4*>(
                &Bm[(long long)(k0 + r) * Nn + bn * BN + c4 * 4]);
            *reinterpret_cast<float4*>(&Bs[r][c4 * 4]) = bv;
        }
        __syncthreads();

#pragma unroll
        for (int kk = 0; kk < BK; kk++) {
            float a[4], b[4];
            const float4 a4 = *reinterpret_cast<const float4*>(&As[kk][tr * 4]);
            const float4 b4 = *reinterpret_cast<const float4*>(&Bs[kk][tc * 4]);
            a[0] = a4.x; a[1] = a4.y; a[2] = a4.z; a[3] = a4.w;
            b[0] = b4.x; b[1] = b4.y; b[2] = b4.z; b[3] = b4.w;
#pragma unroll
            for (int ii = 0; ii < 4; ii++)
#pragma unroll
                for (int jj = 0; jj < 4; jj++)
                    acc[ii][jj] += a[ii] * b[jj];
        }
        __syncthreads();
    }

#pragma unroll
    for (int ii = 0; ii < 4; ii++) {
        const int row = bm * BM + tr * 4 + ii;
#pragma unroll
        for (int jj = 0; jj < 4; jj++) {
            const int col = bn * BN + tc * 4 + jj;
            float v = acc[ii][jj];
            if (bias) v += bias[col];
            C[(long long)row * Nn + col] = v;
        }
    }
}

// ---------------- sigma -> l2r = log2(r) = -log2(e)/(exp(sigmoid(x@Ws+bs))+1) --
// one thread per (row, h); l2rbuf layout: [row][h] (row = b*N + i)
__global__ __launch_bounds__(256) void sigma_kernel(const float* __restrict__ x,
                                                    const float* __restrict__ Ws,
                                                    const float* __restrict__ bs,
                                                    float* __restrict__ l2rbuf) {
    const int gid = blockIdx.x * 256 + threadIdx.x;   // row*8 + h
    const int row = gid >> 3;
    const int h = gid & 7;
    const float* xr = x + (long long)row * D;
    float acc = 0.f;
#pragma unroll 8
    for (int e = 0; e < D; e++) acc += xr[e] * Ws[e * H + h];
    const float z = acc + bs[h];
    const float sig = 1.0f / (1.0f + expf(-z));
    const float s = expf(sig) + 1.0f;
    l2rbuf[gid] = -1.4426950408889634f / s;   // log2(r), r = exp(-1/s)
}

// ---------------- j-sweep windowed attention, 16 query rows per wave ----------
// weights are wave-uniform (depend only on b,h,i); lane = dh index
__global__ __launch_bounds__(256) void attn_sweep(const float* __restrict__ V,
                                                  const float* __restrict__ l2rbuf,
                                                  float* __restrict__ O) {
    const int wid = threadIdx.x >> 6;
    const int lane = threadIdx.x & 63;
    const int gi = blockIdx.x * 4 + wid;       // over (b,h,iblk)
    const int NB = N / QB;                     // 128
    const int iblk = gi % NB;
    const int bh = gi / NB;
    const int h = bh % H;
    const int b = bh / H;
    const int i0 = iblk * QB;

    const float* __restrict__ Vb = V + (size_t)b * N * D + h * DH + lane;

    float l2r[QB], r[QB], rinv[QB], w[QB], acc[QB];
#pragma unroll
    for (int k = 0; k < QB; k++) {
        l2r[k] = l2rbuf[((size_t)(b * N + i0 + k)) * H + h];
        r[k] = exp2f(l2r[k]);
        rinv[k] = exp2f(-l2r[k]);
        acc[k] = 0.f;
    }

    const int jA0 = (i0 >= WIN) ? (i0 - WIN) : 0;
    const int e0 = i0 - jA0;
#pragma unroll
    for (int k = 0; k < QB; k++) w[k] = exp2f(l2r[k] * (float)(e0 + k));

    const float* p = Vb + (size_t)jA0 * D;

    // Phase A: all j < i0 (weights shrink toward j=i: use then *= rinv)
    for (int j = jA0; j < i0; ++j) {
        const float v = *p; p += D;
#pragma unroll
        for (int k = 0; k < QB; k++) { acc[k] += w[k] * v; w[k] *= rinv[k]; }
    }

    // Phase B: j = i0+jj, jj and k both compile-time after full unroll
#pragma unroll
    for (int jj = 0; jj < QB; jj++) {
        const float v = *p; p += D;
#pragma unroll
        for (int k = 0; k < QB; k++) {
            if (jj == k)      { acc[k] += v;        w[k] = r[k];    }  // exact w=1
            else if (jj < k)  { acc[k] += w[k] * v; w[k] *= rinv[k]; }
            else              { acc[k] += w[k] * v; w[k] *= r[k];    }
        }
    }

    // Phase C: all j > i0+QB-1 (weights decay: use then *= r)
    const int jCend = (i0 + QB + WIN < N) ? (i0 + QB + WIN) : N;
    for (int j = i0 + QB; j < jCend; ++j) {
        const float v = *p; p += D;
#pragma unroll
        for (int k = 0; k < QB; k++) { acc[k] += w[k] * v; w[k] *= r[k]; }
    }

    // closed-form softmax denominator: z = 1 + (r - r^(i+1))/(1-r) + (r - r^(N-i))/(1-r)
#pragma unroll
    for (int k = 0; k < QB; k++) {
        const int i = i0 + k;
        const float rr = r[k];
        const float inv1mr = 1.0f / (1.0f - rr);
        const float rl = exp2f(l2r[k] * (float)(i + 1));
        const float rg = exp2f(l2r[k] * (float)(N - i));
        const float z = 1.0f + (rr - rl) * inv1mr + (rr - rg) * inv1mr;
        O[((size_t)(b * N + i)) * D + h * DH + lane] = acc[k] / z;
    }
}

extern "C" void kernel_launch(void* const* d_in, const int* in_sizes, int n_in,
                              void* d_out, int out_size, void* d_ws, size_t ws_size,
                              hipStream_t stream) {
    const float* x      = (const float*)d_in[0];   // (B,N,D)
    const float* W_v    = (const float*)d_in[1];   // (D, H*DH)
    const float* W_sig  = (const float*)d_in[2];   // (D, H)
    const float* b_sig  = (const float*)d_in[3];   // (H,)
    const float* W_out  = (const float*)d_in[4];   // (H*DH, D)
    const float* b_out  = (const float*)d_in[5];   // (D,)
    float* out = (float*)d_out;

    char* ws = (char*)d_ws;
    float* V       = (float*)(ws);                              // ROWS*D f32 = 16 MB
    float* attnOut = (float*)(ws + (size_t)ROWS * D * 4);       // 16 MB
    float* l2rbuf  = (float*)(ws + (size_t)ROWS * D * 8);       // ROWS*H f32 = 256 KB

    // 1) V = x @ W_v
    {
        dim3 grid(D / BN, ROWS / BM);
        gemm_f32<<<grid, 256, 0, stream>>>(x, W_v, nullptr, V, ROWS, D, D);
    }
    // 2) log2(r) per (row, h)
    {
        dim3 grid(ROWS * H / 256);
        sigma_kernel<<<grid, 256, 0, stream>>>(x, W_sig, b_sig, l2rbuf);
    }
    // 3) j-sweep windowed attention
    {
        dim3 grid(B * H * (N / QB) / 4);   // 1024 blocks, 4 waves each
        attn_sweep<<<grid, 256, 0, stream>>>(V, l2rbuf, attnOut);
    }
    // 4) out = attnOut @ W_out + b_out
    {
        dim3 grid(D / BN, ROWS / BM);
        gemm_f32<<<grid, 256, 0, stream>>>(attnOut, W_out, b_out, out, ROWS, D, D);
    }
}

// Round 3
// 115.901 us; speedup vs baseline: 3.1941x; 1.8491x over previous
//
#include <hip/hip_runtime.h>
#include <hip/hip_bf16.h>

// Problem constants
#define B 4
#define N 2048
#define D 512
#define H 8
#define DH 64
#define ROWS (B * N)        // 8192
#define WIN 64              // r<=0.764 -> r^64 ~ 3e-8
#define QB 16               // query rows per wave in attn_sweep

using bf16x8 = __attribute__((ext_vector_type(8))) short;  // 8 bf16 (4 VGPRs)
using f32x4  = __attribute__((ext_vector_type(4))) float;  // MFMA accumulator

static __device__ __forceinline__ unsigned short f2bf(float f) {
    unsigned u = __builtin_bit_cast(unsigned, f);
    u += 0x7fffu + ((u >> 16) & 1u);        // round-to-nearest-even
    return (unsigned short)(u >> 16);
}

// ---------------- x f32 -> bf16 (8 elems/thread) ------------------------------
__global__ __launch_bounds__(256) void cvt_x(const float* __restrict__ x,
                                             unsigned short* __restrict__ xbf) {
    const size_t t = (size_t)blockIdx.x * 256 + threadIdx.x;
    const float4* p = reinterpret_cast<const float4*>(x) + t * 2;
    const float4 a = p[0], b = p[1];
    ushort4 lo, hi;
    lo.x = f2bf(a.x); lo.y = f2bf(a.y); lo.z = f2bf(a.z); lo.w = f2bf(a.w);
    hi.x = f2bf(b.x); hi.y = f2bf(b.y); hi.z = f2bf(b.z); hi.w = f2bf(b.w);
    ushort4* q = reinterpret_cast<ushort4*>(xbf) + t * 2;
    q[0] = lo; q[1] = hi;
}

// ---------------- W (512x512 f32, KxN) -> W^T (NxK bf16) ----------------------
__global__ __launch_bounds__(256) void transpose_cvt(const float* __restrict__ Wv,
                                                     const float* __restrict__ Wo,
                                                     unsigned short* __restrict__ WvT,
                                                     unsigned short* __restrict__ WoT) {
    const float* src = blockIdx.z ? Wo : Wv;
    unsigned short* dst = blockIdx.z ? WoT : WvT;
    __shared__ float tile[64][65];
    const int n0 = blockIdx.x * 64, k0 = blockIdx.y * 64;
    const int tr = threadIdx.x >> 4, tc = threadIdx.x & 15;
#pragma unroll
    for (int it = 0; it < 4; it++) {
        const int r = it * 16 + tr;   // k offset
        const float4 v = *reinterpret_cast<const float4*>(&src[(size_t)(k0 + r) * 512 + n0 + tc * 4]);
        tile[r][tc * 4 + 0] = v.x; tile[r][tc * 4 + 1] = v.y;
        tile[r][tc * 4 + 2] = v.z; tile[r][tc * 4 + 3] = v.w;
    }
    __syncthreads();
#pragma unroll
    for (int it = 0; it < 4; it++) {
        const int r = it * 16 + tr;   // n offset
        ushort4 o;
        o.x = f2bf(tile[tc * 4 + 0][r]); o.y = f2bf(tile[tc * 4 + 1][r]);
        o.z = f2bf(tile[tc * 4 + 2][r]); o.w = f2bf(tile[tc * 4 + 3][r]);
        *reinterpret_cast<ushort4*>(&dst[(size_t)(n0 + r) * 512 + k0 + tc * 4]) = o;
    }
}

// ---------------- sigma -> l2r = log2(r) --------------------------------------
__global__ __launch_bounds__(256) void sigma_kernel(const float* __restrict__ x,
                                                    const float* __restrict__ Ws,
                                                    const float* __restrict__ bs,
                                                    float* __restrict__ l2rbuf) {
    const int gid = blockIdx.x * 256 + threadIdx.x;   // row*8 + h
    const int row = gid >> 3;
    const int h = gid & 7;
    const float4* xr = reinterpret_cast<const float4*>(x + (size_t)row * D);
    float acc = 0.f;
#pragma unroll 4
    for (int e4 = 0; e4 < D / 4; e4++) {
        const float4 v = xr[e4];
        acc += v.x * Ws[(e4 * 4 + 0) * H + h] + v.y * Ws[(e4 * 4 + 1) * H + h]
             + v.z * Ws[(e4 * 4 + 2) * H + h] + v.w * Ws[(e4 * 4 + 3) * H + h];
    }
    const float z = acc + bs[h];
    const float sig = 1.0f / (1.0f + expf(-z));
    const float s = expf(sig) + 1.0f;
    l2rbuf[gid] = -1.4426950408889634f / s;   // log2(r), r = exp(-1/s)
}

// ---------------- bf16 MFMA GEMM: C[M,Nn] = A[M,K] @ Bt[Nn,K]^T (+bias) -------
// m97 structure: linear LDS, global_load_lds width-16 staging, 2 barriers/K-step
#define GBM 128
#define GBN 64
#define GBK 64

__global__ __launch_bounds__(256) void gemm_bf16(const unsigned short* __restrict__ A,
                                                 const unsigned short* __restrict__ Bt,
                                                 const float* __restrict__ bias,
                                                 float* __restrict__ C,
                                                 int M, int Nn, int K) {
    __shared__ unsigned short As[GBM][GBK];   // 16 KB
    __shared__ unsigned short Bs[GBN][GBK];   // 8 KB
    const int tid = threadIdx.x;
    const int lane = tid & 63, wid = tid >> 6;
    const int wr = wid >> 1, wc = wid & 1;    // 2x2 waves: 64x32 each
    const int bm = blockIdx.y, bn = blockIdx.x;
    const int fr = lane & 15, kg = lane >> 4;

    f32x4 acc[4][2] = {};

    const unsigned short* Ab = A + (size_t)bm * GBM * K;
    const unsigned short* Bb = Bt + (size_t)bn * GBN * K;
    const int r8 = tid >> 3, c8 = (tid & 7) * 8;

    for (int k0 = 0; k0 < K; k0 += GBK) {
#pragma unroll
        for (int it = 0; it < 4; it++) {
            const unsigned short* g = Ab + (size_t)(it * 32 + r8) * K + k0 + c8;
            __builtin_amdgcn_global_load_lds(
                (const __attribute__((address_space(1))) void*)g,
                (__attribute__((address_space(3))) void*)&As[it * 32 + r8][c8], 16, 0, 0);
        }
#pragma unroll
        for (int it = 0; it < 2; it++) {
            const unsigned short* g = Bb + (size_t)(it * 32 + r8) * K + k0 + c8;
            __builtin_amdgcn_global_load_lds(
                (const __attribute__((address_space(1))) void*)g,
                (__attribute__((address_space(3))) void*)&Bs[it * 32 + r8][c8], 16, 0, 0);
        }
        __syncthreads();   // compiler drains vmcnt before barrier

#pragma unroll
        for (int ks = 0; ks < 2; ks++) {
            bf16x8 af[4], bfr[2];
#pragma unroll
            for (int m = 0; m < 4; m++)
                af[m] = *reinterpret_cast<const bf16x8*>(&As[wr * 64 + m * 16 + fr][ks * 32 + kg * 8]);
#pragma unroll
            for (int n = 0; n < 2; n++)
                bfr[n] = *reinterpret_cast<const bf16x8*>(&Bs[wc * 32 + n * 16 + fr][ks * 32 + kg * 8]);
#pragma unroll
            for (int m = 0; m < 4; m++)
#pragma unroll
                for (int n = 0; n < 2; n++)
                    acc[m][n] = __builtin_amdgcn_mfma_f32_16x16x32_bf16(af[m], bfr[n], acc[m][n], 0, 0, 0);
        }
        __syncthreads();
    }

#pragma unroll
    for (int n = 0; n < 2; n++) {
        const int col = bn * GBN + wc * 32 + n * 16 + fr;
        const float bv = bias ? bias[col] : 0.0f;
#pragma unroll
        for (int m = 0; m < 4; m++) {
            const int row0 = bm * GBM + wr * 64 + m * 16 + kg * 4;
#pragma unroll
            for (int j = 0; j < 4; j++)
                C[(size_t)(row0 + j) * Nn + col] = acc[m][n][j] + bv;
        }
    }
}

// ---------------- j-sweep windowed attention, 16 query rows per wave ----------
__global__ __launch_bounds__(256) void attn_sweep(const float* __restrict__ V,
                                                  const float* __restrict__ l2rbuf,
                                                  unsigned short* __restrict__ O) {
    const int wid = threadIdx.x >> 6;
    const int lane = threadIdx.x & 63;
    const int gi = blockIdx.x * 4 + wid;       // over (b,h,iblk)
    const int NB = N / QB;                     // 128
    const int iblk = gi % NB;
    const int bh = gi / NB;
    const int h = bh % H;
    const int b = bh / H;
    const int i0 = iblk * QB;

    const float* __restrict__ Vb = V + (size_t)b * N * D + h * DH + lane;

    float l2r[QB], r[QB], rinv[QB], w[QB], acc[QB];
#pragma unroll
    for (int k = 0; k < QB; k++) {
        l2r[k] = l2rbuf[((size_t)(b * N + i0 + k)) * H + h];
        r[k] = exp2f(l2r[k]);
        rinv[k] = exp2f(-l2r[k]);
        acc[k] = 0.f;
    }

    const int jA0 = (i0 >= WIN) ? (i0 - WIN) : 0;
    const int e0 = i0 - jA0;
#pragma unroll
    for (int k = 0; k < QB; k++) w[k] = exp2f(l2r[k] * (float)(e0 + k));

    const float* p = Vb + (size_t)jA0 * D;

    // Phase A: all j < i0
    for (int j = jA0; j < i0; ++j) {
        const float v = *p; p += D;
#pragma unroll
        for (int k = 0; k < QB; k++) { acc[k] += w[k] * v; w[k] *= rinv[k]; }
    }

    // Phase B: 16 mixed steps, fully unrolled (j==i exact w=1 reset)
#pragma unroll
    for (int jj = 0; jj < QB; jj++) {
        const float v = *p; p += D;
#pragma unroll
        for (int k = 0; k < QB; k++) {
            if (jj == k)      { acc[k] += v;        w[k] = r[k];     }
            else if (jj < k)  { acc[k] += w[k] * v; w[k] *= rinv[k]; }
            else              { acc[k] += w[k] * v; w[k] *= r[k];    }
        }
    }

    // Phase C: all j > i0+QB-1
    const int jCend = (i0 + QB + WIN < N) ? (i0 + QB + WIN) : N;
    for (int j = i0 + QB; j < jCend; ++j) {
        const float v = *p; p += D;
#pragma unroll
        for (int k = 0; k < QB; k++) { acc[k] += w[k] * v; w[k] *= r[k]; }
    }

    // closed-form denominator
#pragma unroll
    for (int k = 0; k < QB; k++) {
        const int i = i0 + k;
        const float rr = r[k];
        const float inv1mr = 1.0f / (1.0f - rr);
        const float rl = exp2f(l2r[k] * (float)(i + 1));
        const float rg = exp2f(l2r[k] * (float)(N - i));
        const float z = 1.0f + (rr - rl) * inv1mr + (rr - rg) * inv1mr;
        O[((size_t)(b * N + i)) * D + h * DH + lane] = f2bf(acc[k] / z);
    }
}

extern "C" void kernel_launch(void* const* d_in, const int* in_sizes, int n_in,
                              void* d_out, int out_size, void* d_ws, size_t ws_size,
                              hipStream_t stream) {
    const float* x      = (const float*)d_in[0];   // (B,N,D)
    const float* W_v    = (const float*)d_in[1];   // (D, 512)
    const float* W_sig  = (const float*)d_in[2];   // (D, H)
    const float* b_sig  = (const float*)d_in[3];   // (H,)
    const float* W_out  = (const float*)d_in[4];   // (512, D)
    const float* b_out  = (const float*)d_in[5];   // (D,)
    float* out = (float*)d_out;

    char* ws = (char*)d_ws;
    float*          V    = (float*)ws;                                  // 16 MB
    unsigned short* xbf  = (unsigned short*)(ws + (size_t)16 * 1024 * 1024);  // 8 MB (reused as attnOut)
    unsigned short* WvT  = (unsigned short*)(ws + (size_t)24 * 1024 * 1024);  // 512 KB
    unsigned short* WoT  = (unsigned short*)(ws + (size_t)24 * 1024 * 1024 + 524288);
    float*          l2r  = (float*)(ws + (size_t)25 * 1024 * 1024);     // 256 KB
    unsigned short* attnOut = xbf;   // x_bf dead after GEMM1

    // prep: x->bf16, W transposes, sigma
    cvt_x<<<ROWS * D / (256 * 8), 256, 0, stream>>>(x, xbf);
    {
        dim3 grid(8, 8, 2);
        transpose_cvt<<<grid, 256, 0, stream>>>(W_v, W_out, WvT, WoT);
    }
    sigma_kernel<<<ROWS * H / 256, 256, 0, stream>>>(x, W_sig, b_sig, l2r);

    // 1) V = x @ W_v  (f32 out)
    {
        dim3 grid(D / GBN, ROWS / GBM);
        gemm_bf16<<<grid, 256, 0, stream>>>(xbf, WvT, nullptr, V, ROWS, D, D);
    }
    // 2) windowed attention -> bf16
    attn_sweep<<<B * H * (N / QB) / 4, 256, 0, stream>>>(V, l2r, attnOut);
    // 3) out = attnOut @ W_out + b_out
    {
        dim3 grid(D / GBN, ROWS / GBM);
        gemm_bf16<<<grid, 256, 0, stream>>>(attnOut, WoT, b_out, out, ROWS, D, D);
    }
}